// Round 2
// baseline (452.183 us; speedup 1.0000x reference)
//
#include <hip/hip_runtime.h>

// ---------------------------------------------------------------------------
// GraphVAELoss fused:
//   mega_kernel: blocks [0,2048) = A_recon streaming (268MB), blocks
//                [2048,3072) = KL_i (einsum + KL per node, z_a staged in LDS)
//   finalize_kernel: KL_A (tiny) + slot reductions + output
// ws layout (doubles): [0,2048) arecon partials, [2048,3072) kli partials
// ---------------------------------------------------------------------------

static constexpr int BB  = 32;
static constexpr int NN  = 1024;
static constexpr int ZIc = 64;
static constexpr int ZAc = 128;
static constexpr int AB  = 2048;                  // arecon blocks
static constexpr int KB  = 1024;                  // kli blocks (one per node)
static constexpr int NV4 = (BB * NN * NN) / 4;    // 8,388,608 float4s

#define EPSV 1e-10f
#define SPW  0.7f

// A_true is exactly {0,1}: t==1 -> log(a); t==0 -> 0.7*log(1-a).
// (Bit-identical to t*log(a)+(1-t)*log(1-a) with the t==0 sparsity scale,
//  since the dead branch contributes exactly 0.)  One log instead of two.
__device__ __forceinline__ float ll_elem(float a, float t) {
    a = (a == 0.0f) ? EPSV : ((a == 1.0f) ? (1.0f - EPSV) : a);
    float x = (t == 0.0f) ? (1.0f - a) : a;
    float s = (t == 0.0f) ? SPW : 1.0f;
    return s * __logf(x);
}

__global__ __launch_bounds__(256, 4) void mega_kernel(
        const float4* __restrict__ Ah, const float4* __restrict__ At,
        const float* __restrict__ mu_i, const float* __restrict__ lv_i,
        const float* __restrict__ z_a,
        const float* __restrict__ Bmu, const float* __restrict__ Blv,
        double* __restrict__ slots) {
    __shared__ float  zlds[BB * ZAc];   // 16 KB, kli path only
    __shared__ double dred[4];
    const int lane = threadIdx.x & 63;
    const int wave = threadIdx.x >> 6;

    if (blockIdx.x < AB) {
        // ------------------- A_recon: stream 268 MB -------------------
        float lsum = 0.0f;
        size_t tb = (size_t)blockIdx.x * 1024 + threadIdx.x;
#pragma unroll 2
        for (int s = 0; s < 4; ++s) {           // NV4 = 2048*1024*4 exactly
            float4 a[4], t[4];
#pragma unroll
            for (int k = 0; k < 4; ++k) a[k] = Ah[tb + 256 * k];
#pragma unroll
            for (int k = 0; k < 4; ++k) t[k] = At[tb + 256 * k];
#pragma unroll
            for (int k = 0; k < 4; ++k) {
                lsum += ll_elem(a[k].x, t[k].x);
                lsum += ll_elem(a[k].y, t[k].y);
                lsum += ll_elem(a[k].z, t[k].z);
                lsum += ll_elem(a[k].w, t[k].w);
            }
            tb += (size_t)AB * 1024;
        }
#pragma unroll
        for (int m = 1; m < 64; m <<= 1) lsum += __shfl_xor(lsum, m, 64);
        if (lane == 0) dred[wave] = (double)lsum;
        __syncthreads();
        if (threadIdx.x == 0)
            slots[blockIdx.x] = dred[0] + dred[1] + dred[2] + dred[3];
    } else {
        // ------------------- KL_i: one block per node n -------------------
        const int n = blockIdx.x - AB;
        const int f = lane;
        // stage z_a [32][128] into LDS once (coalesced float4)
        {
            const float4* z4 = reinterpret_cast<const float4*>(z_a);
            float4* zl4 = reinterpret_cast<float4*>(zlds);
#pragma unroll
            for (int k = 0; k < 4; ++k)
                zl4[k * 256 + threadIdx.x] = z4[k * 256 + threadIdx.x];
        }
        __syncthreads();
        const float4* zl4 = reinterpret_cast<const float4*>(zlds);

        const float4* bmu = reinterpret_cast<const float4*>(Bmu + ((size_t)n * ZIc + f) * ZAc);
        const float4* blv = reinterpret_cast<const float4*>(Blv + ((size_t)n * ZIc + f) * ZAc);

        float pm[8], pl[8];
#pragma unroll
        for (int i = 0; i < 8; ++i) { pm[i] = 0.0f; pl[i] = 0.0f; }

#pragma unroll 1
        for (int c = 0; c < 8; ++c) {            // 8 chunks of 16 g-values
            float4 m[4], l[4];
#pragma unroll
            for (int q = 0; q < 4; ++q) { m[q] = bmu[c * 4 + q]; l[q] = blv[c * 4 + q]; }
#pragma unroll
            for (int bi = 0; bi < 8; ++bi) {
                const int b = bi * 4 + wave;
#pragma unroll
                for (int q = 0; q < 4; ++q) {
                    float4 zz = zl4[b * 32 + c * 4 + q];   // wave-uniform -> LDS broadcast
                    pm[bi] += m[q].x * zz.x + m[q].y * zz.y + m[q].z * zz.z + m[q].w * zz.w;
                    pl[bi] += l[q].x * zz.x + l[q].y * zz.y + l[q].z * zz.z + l[q].w * zz.w;
                }
            }
        }

        double local = 0.0;
#pragma unroll
        for (int bi = 0; bi < 8; ++bi) {
            const int b = bi * 4 + wave;
            const size_t base = ((size_t)b * NN + n) * ZIc + f;
            float m1  = mu_i[base];
            float lv1 = lv_i[base];
            float d   = lv1 - pl[bi];               // log-det ratio element
            float dm  = pm[bi] - m1;
            float sc  = __expf(d) + dm * dm * __expf(-pl[bi]);  // trace + inner
            float sd  = d;
#pragma unroll
            for (int m = 1; m < 64; m <<= 1) {
                sd += __shfl_xor(sd, m, 64);
                sc += __shfl_xor(sc, m, 64);
            }
            if (f == 0)
                local += (double)(0.5f * __expf(sd) - 64.0f + sc);
        }
        if (f == 0) dred[wave] = local;
        __syncthreads();
        if (threadIdx.x == 0)
            slots[AB + n] = dred[0] + dred[1] + dred[2] + dred[3];
    }
}

__global__ __launch_bounds__(256) void finalize_kernel(
        const double* __restrict__ ws,
        const float* __restrict__ mu_A, const float* __restrict__ lv_A,
        float* __restrict__ out) {
    const int lane = threadIdx.x & 63;
    const int wave = threadIdx.x >> 6;

    // ---- slot sums ----
    double a = 0.0, ki = 0.0;
    for (int i = threadIdx.x; i < AB; i += 256) a  += ws[i];
    for (int i = threadIdx.x; i < KB; i += 256) ki += ws[AB + i];
#pragma unroll
    for (int m = 1; m < 64; m <<= 1) {
        a  += __shfl_xor(a, m, 64);
        ki += __shfl_xor(ki, m, 64);
    }

    // ---- KL_A: wave w handles b = 8w..8w+7 ----
    double ka = 0.0;
#pragma unroll 1
    for (int bb = 0; bb < 8; ++bb) {
        const int b = wave * 8 + bb;
        float lv0 = lv_A[b * ZAc + lane], lv1 = lv_A[b * ZAc + 64 + lane];
        float m0  = mu_A[b * ZAc + lane], m1  = mu_A[b * ZAc + 64 + lane];
        float slv = lv0 + lv1;
        float sc  = __expf(lv0) + __expf(lv1) + m0 * m0 + m1 * m1;
#pragma unroll
        for (int m = 1; m < 64; m <<= 1) {
            slv += __shfl_xor(slv, m, 64);
            sc  += __shfl_xor(sc, m, 64);
        }
        if (lane == 0)
            ka += (double)(0.5f * __expf(slv) - 128.0f + sc);
    }

    __shared__ double sa[4], ski[4], ska[4];
    if (lane == 0) { sa[wave] = a; ski[wave] = ki; ska[wave] = ka; }
    __syncthreads();
    if (threadIdx.x == 0) {
        double A  = (sa[0] + sa[1] + sa[2] + sa[3]) / 32.0;
        double KI = (ski[0] + ski[1] + ski[2] + ski[3]) / 32.0;
        double KA = (ska[0] + ska[1] + ska[2] + ska[3]) / 32.0;
        out[0] = (float)A;
        out[1] = (float)KA;
        out[2] = (float)KI;
        out[3] = (float)(-(A + KA + KI));
    }
}

extern "C" void kernel_launch(void* const* d_in, const int* in_sizes, int n_in,
                              void* d_out, int out_size, void* d_ws, size_t ws_size,
                              hipStream_t stream) {
    const float* Ah   = (const float*)d_in[0];   // A_hat_batch  [32,1024,1024]
    const float* At   = (const float*)d_in[1];   // A_true       [32,1024,1024]
    const float* mu_A = (const float*)d_in[4];   // [32,128]
    const float* lv_A = (const float*)d_in[5];   // [32,128]
    const float* mu_i = (const float*)d_in[6];   // [32,1024,64]
    const float* lv_i = (const float*)d_in[7];   // [32,1024,64]
    const float* z_a  = (const float*)d_in[8];   // [32,128]
    const float* Bmu  = (const float*)d_in[9];   // [1024,64,128]
    const float* Blv  = (const float*)d_in[10];  // [1024,64,128]

    double* ws = (double*)d_ws;   // 3072 doubles, all written every call
    float* out = (float*)d_out;

    hipLaunchKernelGGL(mega_kernel, dim3(AB + KB), dim3(256), 0, stream,
                       (const float4*)Ah, (const float4*)At,
                       mu_i, lv_i, z_a, Bmu, Blv, ws);
    hipLaunchKernelGGL(finalize_kernel, dim3(1), dim3(256), 0, stream,
                       ws, mu_A, lv_A, out);
}

// Round 3
// 376.675 us; speedup vs baseline: 1.2005x; 1.2005x over previous
//
#include <hip/hip_runtime.h>

// ---------------------------------------------------------------------------
// GraphVAELoss, R3: un-fused (R2's fusion caused a 64-VGPR cap -> 195MB of
// scratch spill, and 16.9KB LDS on all blocks -> occupancy 40%).
//   arecon_kernel : stream A_hat/A_true (268MB), 8 float4-pairs/thread,
//                   deep load batching, no LDS, no launch_bounds cap.
//   kli_kernel    : per-node einsum + KL; z_a via scalar loads (readfirstlane
//                   -> uniform address), B-rows double-buffered in registers.
//   finalize      : slot sums + KL_A + output.
// ws layout (doubles): [0,4096) arecon partials, [4096,5120) kli partials.
// ---------------------------------------------------------------------------

static constexpr int BB  = 32;
static constexpr int NN  = 1024;
static constexpr int ZIc = 64;
static constexpr int ZAc = 128;
static constexpr int AB  = 4096;                  // arecon blocks
static constexpr int KB  = 1024;                  // kli blocks

#define EPSV 1e-10f
#define SPW  0.7f

// A_true is exactly {0,1}: t==1 -> log(a); t==0 -> 0.7*log(1-a).
// Bit-identical to t*log(a)+(1-t)*log(1-a) + sparsity scale on t==0.
__device__ __forceinline__ float ll_elem(float a, float t) {
    a = (a == 0.0f) ? EPSV : ((a == 1.0f) ? (1.0f - EPSV) : a);
    float x = (t == 0.0f) ? (1.0f - a) : a;
    float s = (t == 0.0f) ? SPW : 1.0f;
    return s * __logf(x);
}

__global__ __launch_bounds__(256) void arecon_kernel(
        const float4* __restrict__ Ah, const float4* __restrict__ At,
        double* __restrict__ slots) {
    float lsum = 0.0f;
    // 4096 blocks * 256 thr * 8 float4 = 8,388,608 = 32*1024*1024/4 exactly
    size_t tb = (size_t)blockIdx.x * 1024 + threadIdx.x;
#pragma unroll
    for (int s = 0; s < 2; ++s) {
        float4 a[4], t[4];
#pragma unroll
        for (int k = 0; k < 4; ++k) a[k] = Ah[tb + 256 * k];
#pragma unroll
        for (int k = 0; k < 4; ++k) t[k] = At[tb + 256 * k];
#pragma unroll
        for (int k = 0; k < 4; ++k) {
            lsum += ll_elem(a[k].x, t[k].x);
            lsum += ll_elem(a[k].y, t[k].y);
            lsum += ll_elem(a[k].z, t[k].z);
            lsum += ll_elem(a[k].w, t[k].w);
        }
        tb += (size_t)AB * 1024;
    }
#pragma unroll
    for (int m = 1; m < 64; m <<= 1) lsum += __shfl_xor(lsum, m, 64);
    __shared__ float wsum[4];
    const int lane = threadIdx.x & 63, wv = threadIdx.x >> 6;
    if (lane == 0) wsum[wv] = lsum;
    __syncthreads();
    if (threadIdx.x == 0)
        slots[blockIdx.x] = (double)(wsum[0] + wsum[1] + wsum[2] + wsum[3]);
}

// One block per node n; wave w owns b in [8w, 8w+8); lane f owns feature row f.
// z_a addresses are scalar (readfirstlane-forced wave id) -> scalar-cache
// loads, zero VALU/LDS cost. B rows double-buffered in NAMED register sets
// (runtime-indexed arrays would go to scratch).
__global__ __launch_bounds__(256) void kli_kernel(
        const float* __restrict__ mu_i, const float* __restrict__ lv_i,
        const float* __restrict__ z_a,
        const float* __restrict__ Bmu, const float* __restrict__ Blv,
        double* __restrict__ slots) {
    const int n    = blockIdx.x;
    const int wave = __builtin_amdgcn_readfirstlane(threadIdx.x >> 6);
    const int f    = threadIdx.x & 63;

    const float4* bmu = reinterpret_cast<const float4*>(Bmu + ((size_t)n * ZIc + f) * ZAc);
    const float4* blv = reinterpret_cast<const float4*>(Blv + ((size_t)n * ZIc + f) * ZAc);

    float pm[8], pl[8];
#pragma unroll
    for (int i = 0; i < 8; ++i) { pm[i] = 0.0f; pl[i] = 0.0f; }

    float4 mA[4], lA[4], mB[4], lB[4];
#pragma unroll
    for (int q = 0; q < 4; ++q) { mA[q] = bmu[q]; lA[q] = blv[q]; }

#define KLI_COMPUTE(MV, LV, CC)                                               \
    {                                                                         \
        _Pragma("unroll")                                                     \
        for (int bi = 0; bi < 8; ++bi) {                                      \
            const int b = wave * 8 + bi;                                      \
            const float* zp = z_a + b * ZAc + (CC) * 16;                      \
            _Pragma("unroll")                                                 \
            for (int q = 0; q < 4; ++q) {                                     \
                float4 zz = *reinterpret_cast<const float4*>(zp + 4 * q);     \
                pm[bi] += MV[q].x * zz.x + MV[q].y * zz.y +                   \
                          MV[q].z * zz.z + MV[q].w * zz.w;                    \
                pl[bi] += LV[q].x * zz.x + LV[q].y * zz.y +                   \
                          LV[q].z * zz.z + LV[q].w * zz.w;                    \
            }                                                                 \
        }                                                                     \
    }

#pragma unroll 1
    for (int c = 0; c < 8; c += 2) {
#pragma unroll
        for (int q = 0; q < 4; ++q) { mB[q] = bmu[(c + 1) * 4 + q]; lB[q] = blv[(c + 1) * 4 + q]; }
        KLI_COMPUTE(mA, lA, c)
        if (c + 2 < 8) {
#pragma unroll
            for (int q = 0; q < 4; ++q) { mA[q] = bmu[(c + 2) * 4 + q]; lA[q] = blv[(c + 2) * 4 + q]; }
        }
        KLI_COMPUTE(mB, lB, c + 1)
    }
#undef KLI_COMPUTE

    double local = 0.0;
#pragma unroll
    for (int bi = 0; bi < 8; ++bi) {
        const int b = wave * 8 + bi;
        const size_t base = ((size_t)b * NN + n) * ZIc + f;
        float m1  = mu_i[base];
        float lv1 = lv_i[base];
        float d   = lv1 - pl[bi];                   // log-det ratio element
        float dm  = pm[bi] - m1;
        float sc  = __expf(d) + dm * dm * __expf(-pl[bi]);   // trace + inner
        float sd  = d;
#pragma unroll
        for (int m = 1; m < 64; m <<= 1) {
            sd += __shfl_xor(sd, m, 64);
            sc += __shfl_xor(sc, m, 64);
        }
        if (f == 0)
            local += (double)(0.5f * __expf(sd) - 64.0f + sc);
    }
    __shared__ double wacc[4];
    if (f == 0) wacc[wave] = local;
    __syncthreads();
    if (threadIdx.x == 0)
        slots[n] = wacc[0] + wacc[1] + wacc[2] + wacc[3];
}

__global__ __launch_bounds__(256) void finalize_kernel(
        const double* __restrict__ ws,
        const float* __restrict__ mu_A, const float* __restrict__ lv_A,
        float* __restrict__ out) {
    const int lane = threadIdx.x & 63;
    const int wave = threadIdx.x >> 6;

    double a = 0.0, ki = 0.0;
    const double2* w2 = reinterpret_cast<const double2*>(ws);
    for (int i = threadIdx.x; i < AB / 2; i += 256) { double2 v = w2[i]; a += v.x + v.y; }
    for (int i = threadIdx.x; i < KB / 2; i += 256) { double2 v = w2[AB / 2 + i]; ki += v.x + v.y; }
#pragma unroll
    for (int m = 1; m < 64; m <<= 1) {
        a  += __shfl_xor(a, m, 64);
        ki += __shfl_xor(ki, m, 64);
    }

    // KL_A vs standard normal: wave w handles b = 8w..8w+7
    double ka = 0.0;
#pragma unroll 1
    for (int bb = 0; bb < 8; ++bb) {
        const int b = wave * 8 + bb;
        float lv0 = lv_A[b * ZAc + lane], lv1 = lv_A[b * ZAc + 64 + lane];
        float m0  = mu_A[b * ZAc + lane], m1  = mu_A[b * ZAc + 64 + lane];
        float slv = lv0 + lv1;
        float sc  = __expf(lv0) + __expf(lv1) + m0 * m0 + m1 * m1;
#pragma unroll
        for (int m = 1; m < 64; m <<= 1) {
            slv += __shfl_xor(slv, m, 64);
            sc  += __shfl_xor(sc, m, 64);
        }
        if (lane == 0)
            ka += (double)(0.5f * __expf(slv) - 128.0f + sc);
    }

    __shared__ double sa[4], ski[4], ska[4];
    if (lane == 0) { sa[wave] = a; ski[wave] = ki; ska[wave] = ka; }
    __syncthreads();
    if (threadIdx.x == 0) {
        double A  = (sa[0] + sa[1] + sa[2] + sa[3]) / 32.0;
        double KI = (ski[0] + ski[1] + ski[2] + ski[3]) / 32.0;
        double KA = (ska[0] + ska[1] + ska[2] + ska[3]) / 32.0;
        out[0] = (float)A;
        out[1] = (float)KA;
        out[2] = (float)KI;
        out[3] = (float)(-(A + KA + KI));
    }
}

extern "C" void kernel_launch(void* const* d_in, const int* in_sizes, int n_in,
                              void* d_out, int out_size, void* d_ws, size_t ws_size,
                              hipStream_t stream) {
    const float* Ah   = (const float*)d_in[0];   // A_hat_batch  [32,1024,1024]
    const float* At   = (const float*)d_in[1];   // A_true       [32,1024,1024]
    const float* mu_A = (const float*)d_in[4];   // [32,128]
    const float* lv_A = (const float*)d_in[5];   // [32,128]
    const float* mu_i = (const float*)d_in[6];   // [32,1024,64]
    const float* lv_i = (const float*)d_in[7];   // [32,1024,64]
    const float* z_a  = (const float*)d_in[8];   // [32,128]
    const float* Bmu  = (const float*)d_in[9];   // [1024,64,128]
    const float* Blv  = (const float*)d_in[10];  // [1024,64,128]

    double* ws = (double*)d_ws;   // 5120 doubles = 40 KB, all written every call
    float* out = (float*)d_out;

    hipLaunchKernelGGL(arecon_kernel, dim3(AB), dim3(256), 0, stream,
                       (const float4*)Ah, (const float4*)At, ws);
    hipLaunchKernelGGL(kli_kernel, dim3(KB), dim3(256), 0, stream,
                       mu_i, lv_i, z_a, Bmu, Blv, ws + AB);
    hipLaunchKernelGGL(finalize_kernel, dim3(1), dim3(256), 0, stream,
                       ws, mu_A, lv_A, out);
}

// Round 5
// 368.517 us; speedup vs baseline: 1.2270x; 1.0221x over previous
//
#include <hip/hip_runtime.h>

// ---------------------------------------------------------------------------
// GraphVAELoss, R5 (= R4 resubmitted; R4 bench never acquired a GPU).
// Change vs R3: arecon only.
// R3 evidence: VGPR_Count=24 -> compiler sank all loads to uses (1-2 in
// flight/thread), latency-bound at 2.7 TB/s aggregate. Fix: 16 NAMED float4
// loads issued up front (interleaved a,t pairs) + sched_barrier(0) fence so
// the whole cluster stays in flight (~16KB/wave), then compute.
// kli / finalize unchanged (attribution).
// ws layout (doubles): [0,4096) arecon partials, [4096,5120) kli partials.
// ---------------------------------------------------------------------------

static constexpr int BB  = 32;
static constexpr int NN  = 1024;
static constexpr int ZIc = 64;
static constexpr int ZAc = 128;
static constexpr int AB  = 4096;                  // arecon blocks
static constexpr int KB  = 1024;                  // kli blocks

#define EPSV 1e-10f
#define SPW  0.7f

// A_true is exactly {0,1}: t==1 -> log(a); t==0 -> 0.7*log(1-a).
// Bit-identical to t*log(a)+(1-t)*log(1-a) + sparsity scale on t==0.
__device__ __forceinline__ float ll_elem(float a, float t) {
    a = (a == 0.0f) ? EPSV : ((a == 1.0f) ? (1.0f - EPSV) : a);
    float x = (t == 0.0f) ? (1.0f - a) : a;
    float s = (t == 0.0f) ? SPW : 1.0f;
    return s * __logf(x);
}

__device__ __forceinline__ float ll4(float4 a, float4 t) {
    return ll_elem(a.x, t.x) + ll_elem(a.y, t.y) +
           ll_elem(a.z, t.z) + ll_elem(a.w, t.w);
}

__global__ __launch_bounds__(256) void arecon_kernel(
        const float4* __restrict__ Ah, const float4* __restrict__ At,
        double* __restrict__ slots) {
    // 4096 blocks * 256 thr * 8 float4 = 8,388,608 = 32*1024*1024/4 exactly
    const size_t base = (size_t)blockIdx.x * 2048 + threadIdx.x;

    // Issue all 16 loads (interleaved pairs) BEFORE any compute; the
    // sched_barrier(0) forbids the scheduler from sinking them to uses.
    float4 a0 = Ah[base +    0];  float4 t0 = At[base +    0];
    float4 a1 = Ah[base +  256];  float4 t1 = At[base +  256];
    float4 a2 = Ah[base +  512];  float4 t2 = At[base +  512];
    float4 a3 = Ah[base +  768];  float4 t3 = At[base +  768];
    float4 a4 = Ah[base + 1024];  float4 t4 = At[base + 1024];
    float4 a5 = Ah[base + 1280];  float4 t5 = At[base + 1280];
    float4 a6 = Ah[base + 1536];  float4 t6 = At[base + 1536];
    float4 a7 = Ah[base + 1792];  float4 t7 = At[base + 1792];
    __builtin_amdgcn_sched_barrier(0);

    float lsum = 0.0f;
    lsum += ll4(a0, t0);
    lsum += ll4(a1, t1);
    lsum += ll4(a2, t2);
    lsum += ll4(a3, t3);
    lsum += ll4(a4, t4);
    lsum += ll4(a5, t5);
    lsum += ll4(a6, t6);
    lsum += ll4(a7, t7);

#pragma unroll
    for (int m = 1; m < 64; m <<= 1) lsum += __shfl_xor(lsum, m, 64);
    __shared__ float wsum[4];
    const int lane = threadIdx.x & 63, wv = threadIdx.x >> 6;
    if (lane == 0) wsum[wv] = lsum;
    __syncthreads();
    if (threadIdx.x == 0)
        slots[blockIdx.x] = (double)(wsum[0] + wsum[1] + wsum[2] + wsum[3]);
}

// One block per node n; wave w owns b in [8w, 8w+8); lane f owns feature row f.
// z_a addresses are scalar (readfirstlane-forced wave id) -> scalar-cache
// loads. B rows double-buffered in NAMED register sets (no runtime-indexed
// arrays -> no scratch).
__global__ __launch_bounds__(256) void kli_kernel(
        const float* __restrict__ mu_i, const float* __restrict__ lv_i,
        const float* __restrict__ z_a,
        const float* __restrict__ Bmu, const float* __restrict__ Blv,
        double* __restrict__ slots) {
    const int n    = blockIdx.x;
    const int wave = __builtin_amdgcn_readfirstlane(threadIdx.x >> 6);
    const int f    = threadIdx.x & 63;

    const float4* bmu = reinterpret_cast<const float4*>(Bmu + ((size_t)n * ZIc + f) * ZAc);
    const float4* blv = reinterpret_cast<const float4*>(Blv + ((size_t)n * ZIc + f) * ZAc);

    float pm[8], pl[8];
#pragma unroll
    for (int i = 0; i < 8; ++i) { pm[i] = 0.0f; pl[i] = 0.0f; }

    float4 mA[4], lA[4], mB[4], lB[4];
#pragma unroll
    for (int q = 0; q < 4; ++q) { mA[q] = bmu[q]; lA[q] = blv[q]; }

#define KLI_COMPUTE(MV, LV, CC)                                               \
    {                                                                         \
        _Pragma("unroll")                                                     \
        for (int bi = 0; bi < 8; ++bi) {                                      \
            const int b = wave * 8 + bi;                                      \
            const float* zp = z_a + b * ZAc + (CC) * 16;                      \
            _Pragma("unroll")                                                 \
            for (int q = 0; q < 4; ++q) {                                     \
                float4 zz = *reinterpret_cast<const float4*>(zp + 4 * q);     \
                pm[bi] += MV[q].x * zz.x + MV[q].y * zz.y +                   \
                          MV[q].z * zz.z + MV[q].w * zz.w;                    \
                pl[bi] += LV[q].x * zz.x + LV[q].y * zz.y +                   \
                          LV[q].z * zz.z + LV[q].w * zz.w;                    \
            }                                                                 \
        }                                                                     \
    }

#pragma unroll 1
    for (int c = 0; c < 8; c += 2) {
#pragma unroll
        for (int q = 0; q < 4; ++q) { mB[q] = bmu[(c + 1) * 4 + q]; lB[q] = blv[(c + 1) * 4 + q]; }
        KLI_COMPUTE(mA, lA, c)
        if (c + 2 < 8) {
#pragma unroll
            for (int q = 0; q < 4; ++q) { mA[q] = bmu[(c + 2) * 4 + q]; lA[q] = blv[(c + 2) * 4 + q]; }
        }
        KLI_COMPUTE(mB, lB, c + 1)
    }
#undef KLI_COMPUTE

    double local = 0.0;
#pragma unroll
    for (int bi = 0; bi < 8; ++bi) {
        const int b = wave * 8 + bi;
        const size_t base = ((size_t)b * NN + n) * ZIc + f;
        float m1  = mu_i[base];
        float lv1 = lv_i[base];
        float d   = lv1 - pl[bi];                   // log-det ratio element
        float dm  = pm[bi] - m1;
        float sc  = __expf(d) + dm * dm * __expf(-pl[bi]);   // trace + inner
        float sd  = d;
#pragma unroll
        for (int m = 1; m < 64; m <<= 1) {
            sd += __shfl_xor(sd, m, 64);
            sc += __shfl_xor(sc, m, 64);
        }
        if (f == 0)
            local += (double)(0.5f * __expf(sd) - 64.0f + sc);
    }
    __shared__ double wacc[4];
    if (f == 0) wacc[wave] = local;
    __syncthreads();
    if (threadIdx.x == 0)
        slots[n] = wacc[0] + wacc[1] + wacc[2] + wacc[3];
}

__global__ __launch_bounds__(256) void finalize_kernel(
        const double* __restrict__ ws,
        const float* __restrict__ mu_A, const float* __restrict__ lv_A,
        float* __restrict__ out) {
    const int lane = threadIdx.x & 63;
    const int wave = threadIdx.x >> 6;

    double a = 0.0, ki = 0.0;
    const double2* w2 = reinterpret_cast<const double2*>(ws);
    for (int i = threadIdx.x; i < AB / 2; i += 256) { double2 v = w2[i]; a += v.x + v.y; }
    for (int i = threadIdx.x; i < KB / 2; i += 256) { double2 v = w2[AB / 2 + i]; ki += v.x + v.y; }
#pragma unroll
    for (int m = 1; m < 64; m <<= 1) {
        a  += __shfl_xor(a, m, 64);
        ki += __shfl_xor(ki, m, 64);
    }

    // KL_A vs standard normal: wave w handles b = 8w..8w+7
    double ka = 0.0;
#pragma unroll 1
    for (int bb = 0; bb < 8; ++bb) {
        const int b = wave * 8 + bb;
        float lv0 = lv_A[b * ZAc + lane], lv1 = lv_A[b * ZAc + 64 + lane];
        float m0  = mu_A[b * ZAc + lane], m1  = mu_A[b * ZAc + 64 + lane];
        float slv = lv0 + lv1;
        float sc  = __expf(lv0) + __expf(lv1) + m0 * m0 + m1 * m1;
#pragma unroll
        for (int m = 1; m < 64; m <<= 1) {
            slv += __shfl_xor(slv, m, 64);
            sc  += __shfl_xor(sc, m, 64);
        }
        if (lane == 0)
            ka += (double)(0.5f * __expf(slv) - 128.0f + sc);
    }

    __shared__ double sa[4], ski[4], ska[4];
    if (lane == 0) { sa[wave] = a; ski[wave] = ki; ska[wave] = ka; }
    __syncthreads();
    if (threadIdx.x == 0) {
        double A  = (sa[0] + sa[1] + sa[2] + sa[3]) / 32.0;
        double KI = (ski[0] + ski[1] + ski[2] + ski[3]) / 32.0;
        double KA = (ska[0] + ska[1] + ska[2] + ska[3]) / 32.0;
        out[0] = (float)A;
        out[1] = (float)KA;
        out[2] = (float)KI;
        out[3] = (float)(-(A + KA + KI));
    }
}

extern "C" void kernel_launch(void* const* d_in, const int* in_sizes, int n_in,
                              void* d_out, int out_size, void* d_ws, size_t ws_size,
                              hipStream_t stream) {
    const float* Ah   = (const float*)d_in[0];   // A_hat_batch  [32,1024,1024]
    const float* At   = (const float*)d_in[1];   // A_true       [32,1024,1024]
    const float* mu_A = (const float*)d_in[4];   // [32,128]
    const float* lv_A = (const float*)d_in[5];   // [32,128]
    const float* mu_i = (const float*)d_in[6];   // [32,1024,64]
    const float* lv_i = (const float*)d_in[7];   // [32,1024,64]
    const float* z_a  = (const float*)d_in[8];   // [32,128]
    const float* Bmu  = (const float*)d_in[9];   // [1024,64,128]
    const float* Blv  = (const float*)d_in[10];  // [1024,64,128]

    double* ws = (double*)d_ws;   // 5120 doubles = 40 KB, all written every call
    float* out = (float*)d_out;

    hipLaunchKernelGGL(arecon_kernel, dim3(AB), dim3(256), 0, stream,
                       (const float4*)Ah, (const float4*)At, ws);
    hipLaunchKernelGGL(kli_kernel, dim3(KB), dim3(256), 0, stream,
                       mu_i, lv_i, z_a, Bmu, Blv, ws + AB);
    hipLaunchKernelGGL(finalize_kernel, dim3(1), dim3(256), 0, stream,
                       ws, mu_A, lv_A, out);
}